// Round 2
// baseline (475.321 us; speedup 1.0000x reference)
//
#include <hip/hip_runtime.h>

#define NN 10000      // nodes
#define NE 320000     // edges
#define DD 128        // feature dim
#define NH 8          // heads

typedef __attribute__((ext_vector_type(8)))  __bf16        bf16x8;
typedef __attribute__((ext_vector_type(8)))  unsigned short ushort8v;
typedef __attribute__((ext_vector_type(16))) float         f32x16;

__device__ __forceinline__ unsigned short f2b(float f) {
  unsigned int b = __builtin_bit_cast(unsigned int, f);
  b += 0x7FFFu + ((b >> 16) & 1u);          // RNE to bf16
  return (unsigned short)(b >> 16);
}
__device__ __forceinline__ float b2f(unsigned short u) {
  return __builtin_bit_cast(float, (unsigned int)u << 16);
}
__device__ __forceinline__ f32x16 mfma32(bf16x8 a, bf16x8 b, f32x16 c) {
  return __builtin_amdgcn_mfma_f32_32x32x16_bf16(a, b, c, 0, 0, 0);
}
__device__ __forceinline__ float exp_fast(float x) {
  return __builtin_amdgcn_exp2f(x * 1.44269504f);
}
__device__ __forceinline__ float silu_fast(float x) {
  float e = __builtin_amdgcn_exp2f(x * -1.44269504f);
  return x * __builtin_amdgcn_rcpf(1.0f + e);
}

// ---- transpose/convert weights: W1T[n][k]=We1[k][n] (bf16), W2T, WgT (padded 8->32) ----
__global__ __launch_bounds__(256) void prep_weights_k(
    const float* We1, const float* We2, const float* Wg,
    unsigned short* W1T, unsigned short* W2T, unsigned short* WgT)
{
  int idx = blockIdx.x * 256 + threadIdx.x;
  if (idx < 384 * 128) {
    int n = idx / 384, k = idx - n * 384;
    W1T[idx] = f2b(We1[k * 128 + n]);
  } else if (idx < 384 * 128 + 128 * 128) {
    int o = idx - 384 * 128;
    int n = o >> 7, k = o & 127;
    W2T[o] = f2b(We2[k * 128 + n]);
  } else if (idx < 384 * 128 + 128 * 128 + 32 * 128) {
    int o = idx - (384 * 128 + 128 * 128);
    int n = o >> 7, k = o & 127;
    WgT[o] = (n < 8) ? f2b(Wg[k * 8 + n]) : (unsigned short)0;
  }
}

// ---- per-node Q/K/V projections (f32), 4 nodes per 128-thread block ----
__global__ __launch_bounds__(128) void node_proj_k(
    const float* h, const float* Wq, const float* bq,
    const float* Wk, const float* bk, const float* Wv, const float* bv,
    float* Q, float* K, float* V)
{
  __shared__ float hs[4][132];
  int g = threadIdx.x >> 5, la = threadIdx.x & 31;
  int n = blockIdx.x * 4 + g;
  float4 hv = *(const float4*)(h + (size_t)n * DD + la * 4);
  hs[g][la*4+0] = hv.x; hs[g][la*4+1] = hv.y; hs[g][la*4+2] = hv.z; hs[g][la*4+3] = hv.w;
  __syncthreads();
  float4 q = *(const float4*)(bq + la * 4);
  float4 k = *(const float4*)(bk + la * 4);
  float4 v = *(const float4*)(bv + la * 4);
  for (int kk = 0; kk < DD; ++kk) {
    float a = hs[g][kk];
    float4 wq = *(const float4*)(Wq + (size_t)kk * DD + la * 4);
    float4 wk = *(const float4*)(Wk + (size_t)kk * DD + la * 4);
    float4 wv = *(const float4*)(Wv + (size_t)kk * DD + la * 4);
    q.x += a * wq.x; q.y += a * wq.y; q.z += a * wq.z; q.w += a * wq.w;
    k.x += a * wk.x; k.y += a * wk.y; k.z += a * wk.z; k.w += a * wk.w;
    v.x += a * wv.x; v.y += a * wv.y; v.z += a * wv.z; v.w += a * wv.w;
  }
  *(float4*)(Q + (size_t)n * DD + la * 4) = q;
  *(float4*)(K + (size_t)n * DD + la * 4) = k;
  *(float4*)(V + (size_t)n * DD + la * 4) = v;
}

// ---- logitsT[h][e] = qk/4 + bg; also builds dst-degree histogram (fused hist) ----
__global__ __launch_bounds__(256) void qk_k(const int* ei, const float* Q, const float* K,
                                            const float* bg, float* logitsT, int* deg)
{
  int e  = blockIdx.x * 32 + (threadIdx.x & 31);
  int h8 = threadIdx.x >> 5;
  int s  = ei[e];
  int d2 = ei[NE + e];
  if (h8 == 0) atomicAdd(&deg[d2], 1);
  const float4* qr = (const float4*)(Q + (size_t)d2 * DD + h8 * 16);
  const float4* kr = (const float4*)(K + (size_t)s  * DD + h8 * 16);
  float acc = 0.f;
#pragma unroll
  for (int i = 0; i < 4; ++i) {
    float4 a = qr[i], b = kr[i];
    acc += a.x*b.x + a.y*b.y + a.z*b.z + a.w*b.w;
  }
  logitsT[(size_t)h8 * NE + e] = acc * 0.25f + bg[h8];
}

// ---- convert t->bf16 (optional store) + gate via MFMA, add into logitsT ----
__global__ __launch_bounds__(64) void t_gate_k(const float* t_ij, unsigned short* tb,
                                               const unsigned short* WgT, float* logitsT,
                                               int write_tb)
{
  __shared__ unsigned short T[32][136];
  int e0 = blockIdx.x * 32;
  int lane = threadIdx.x;
  const float4* tp = (const float4*)(t_ij + (size_t)e0 * DD);
#pragma unroll
  for (int i = 0; i < 16; ++i) {
    int gi = lane + i * 64;          // 1024 float4 = 32 rows x 128
    float4 v = tp[gi];
    int row = gi >> 5, c4 = gi & 31;
    ushort4 u; u.x = f2b(v.x); u.y = f2b(v.y); u.z = f2b(v.z); u.w = f2b(v.w);
    *(ushort4*)&T[row][c4 * 4] = u;
    if (write_tb) *(ushort4*)(tb + (size_t)(e0 + row) * DD + c4 * 4) = u;
  }
  __syncthreads();
  int la = lane & 31, hi = lane >> 5;
  f32x16 acc{};
  const unsigned short* wp = WgT + (size_t)la * DD + hi * 8;
#pragma unroll
  for (int ks = 0; ks < 8; ++ks) {
    bf16x8 a = *(const bf16x8*)&T[la][ks * 16 + hi * 8];
    bf16x8 b = *(const bf16x8*)(wp + ks * 16);
    acc = mfma32(a, b, acc);
  }
  if (la < 8) {
#pragma unroll
    for (int r = 0; r < 16; ++r) {
      int row = (r & 3) + 8 * (r >> 2) + 4 * hi;
      logitsT[(size_t)la * NE + e0 + row] += acc[r];
    }
  }
}

// ---- global per-head softmax denominator (no max-shift needed: logits are O(10)) ----
__global__ __launch_bounds__(256) void sumexp_part_k(const float* logitsT, float* partial) {
  int hh = blockIdx.y, b = blockIdx.x;
  const float* p = logitsT + (size_t)hh * NE + (size_t)b * 5000;
  float s = 0.f;
  for (int i = threadIdx.x; i < 5000; i += 256) s += exp_fast(p[i]);
  __shared__ float red[256];
  red[threadIdx.x] = s;
  __syncthreads();
  for (int k = 128; k > 0; k >>= 1) {
    if (threadIdx.x < k) red[threadIdx.x] += red[threadIdx.x + k];
    __syncthreads();
  }
  if (threadIdx.x == 0) partial[hh * 64 + b] = red[0];
}

__global__ void sumexp_fin_k(const float* partial, float* rs) {
  int hh = threadIdx.x;
  if (hh < 8) {
    float s = 0.f;
    for (int i = 0; i < 64; ++i) s += partial[hh * 64 + i];
    rs[hh] = 1.0f / s;
  }
}

// ---- single-block shuffle scan over deg -> exclusive offs ----
__global__ __launch_bounds__(1024) void scan_k(const int* deg, int* offs) {
  __shared__ int ws[16];
  __shared__ int tot;
  int tid = threadIdx.x;
  int base = tid * 10;
  int v[10]; int s = 0;
#pragma unroll
  for (int j = 0; j < 10; ++j) {
    int i = base + j;
    int d = (i < NN) ? deg[i] : 0;
    v[j] = s; s += d;
  }
  int x = s;
#pragma unroll
  for (int off = 1; off < 64; off <<= 1) {
    int y = __shfl_up(x, off, 64);
    if ((tid & 63) >= off) x += y;        // inclusive wave scan
  }
  if ((tid & 63) == 63) ws[tid >> 6] = x;
  __syncthreads();
  if (tid == 0) {
    int c = 0;
#pragma unroll
    for (int k = 0; k < 16; ++k) { int t = ws[k]; ws[k] = c; c += t; }
    tot = c;
  }
  __syncthreads();
  int texcl = ws[tid >> 6] + (x - s);     // exclusive prefix of this thread's chunk
#pragma unroll
  for (int j = 0; j < 10; ++j) {
    int i = base + j;
    if (i < NN) offs[i] = texcl + v[j];
  }
  if (tid == 0) offs[NN] = tot;
}

__global__ __launch_bounds__(256) void bucket_k(const int* ei, const int* offs,
                                                int* cursor, int* elist) {
  int e = blockIdx.x * 256 + threadIdx.x;
  int d2 = ei[NE + e];
  int p = atomicAdd(&cursor[d2], 1);
  elist[offs[d2] + p] = e;
}

// ---- gather-sum per node: h_agg[n][d] = sum_e alpha[e][d/16] * V[src[e]][d] ----
__global__ __launch_bounds__(128) void aggregate_k(const int* ei, const int* offs, const int* elist,
                                                   const float* logitsT, const float* rs,
                                                   const float* V, float* h_agg)
{
  int n = blockIdx.x, d = threadIdx.x;
  float rsv = rs[d >> 4];
  const size_t hoff = (size_t)(d >> 4) * NE;
  int st = offs[n], en = offs[n + 1];
  float acc = 0.f;
  for (int i = st; i < en; ++i) {
    int e = elist[i];
    int s = ei[e];
    float a = exp_fast(logitsT[hoff + e]) * rsv;
    acc += a * V[(size_t)s * DD + d];
  }
  h_agg[(size_t)n * DD + d] = acc;
}

// ---- h_new = h + h_agg @ Wo + bo  (f32 to d_out, bf16 copy for MLP) ----
__global__ __launch_bounds__(128) void hnew_k(const float* h, const float* h_agg,
                                              const float* Wo, const float* bo,
                                              float* out_h, unsigned short* hnb)
{
  __shared__ float ag[4][132];
  int g = threadIdx.x >> 5, la = threadIdx.x & 31;
  int n = blockIdx.x * 4 + g;
  float4 av = *(const float4*)(h_agg + (size_t)n * DD + la * 4);
  ag[g][la*4+0] = av.x; ag[g][la*4+1] = av.y; ag[g][la*4+2] = av.z; ag[g][la*4+3] = av.w;
  __syncthreads();
  float4 acc = *(const float4*)(bo + la * 4);
  for (int kk = 0; kk < DD; ++kk) {
    float a = ag[g][kk];
    float4 w = *(const float4*)(Wo + (size_t)kk * DD + la * 4);
    acc.x += a * w.x; acc.y += a * w.y; acc.z += a * w.z; acc.w += a * w.w;
  }
  float4 hv = *(const float4*)(h + (size_t)n * DD + la * 4);
  acc.x += hv.x; acc.y += hv.y; acc.z += hv.z; acc.w += hv.w;
  *(float4*)(out_h + (size_t)n * DD + la * 4) = acc;
  ushort4 u; u.x = f2b(acc.x); u.y = f2b(acc.y); u.z = f2b(acc.z); u.w = f2b(acc.w);
  *(ushort4*)(hnb + (size_t)n * DD + la * 4) = u;
}

// ---- edge MLP: t_out = t + silu([hn[src],hn[dst],t] @ We1 + be1) @ We2 + be2 ----
// 64 edges/block, 8 waves: wave = (row-half, col-slab); each wave one 32x32 tile.
template <bool TB>
__global__ __launch_bounds__(512) void edge_mlp_k(
    const int* ei, const unsigned short* hnb, const unsigned short* tb, const float* t_ij,
    const unsigned short* W1T, const unsigned short* W2T,
    const float* be1, const float* be2, float* t_out)
{
  __shared__ unsigned short Ah[64][264];   // cols 0..255 = h_src | h_dst (then reused as Y)
  __shared__ unsigned short Tl[64][136];   // t section (kept for epilogue residual)
  __shared__ int sd[128];
  int tid = threadIdx.x;
  int e0 = blockIdx.x * 64;
  if (tid < 128) sd[tid] = (tid < 64) ? ei[e0 + tid] : ei[NE + e0 + tid - 64];
  __syncthreads();
#pragma unroll
  for (int i = 0; i < 4; ++i) {            // 2048 16B chunks for the two h sections
    int c = tid + i * 512;
    int sec = c >> 10;
    int row = (c >> 4) & 63;
    int cc = c & 15;
    int node = sd[sec * 64 + row];
    ushort8v val = *(const ushort8v*)(hnb + (size_t)node * DD + cc * 8);
    *(ushort8v*)&Ah[row][sec * 128 + cc * 8] = val;
  }
  if (TB) {
#pragma unroll
    for (int i = 0; i < 2; ++i) {
      int c = tid + i * 512;
      int row = c >> 4, cc = c & 15;
      *(ushort8v*)&Tl[row][cc * 8] = *(const ushort8v*)(tb + (size_t)(e0 + row) * DD + cc * 8);
    }
  } else {
#pragma unroll
    for (int i = 0; i < 2; ++i) {
      int c = tid + i * 512;
      int row = c >> 4, cc = c & 15;
      const float4* fp = (const float4*)(t_ij + (size_t)(e0 + row) * DD + cc * 8);
      float4 v0 = fp[0], v1 = fp[1];
      ushort4 u0; u0.x=f2b(v0.x); u0.y=f2b(v0.y); u0.z=f2b(v0.z); u0.w=f2b(v0.w);
      ushort4 u1; u1.x=f2b(v1.x); u1.y=f2b(v1.y); u1.z=f2b(v1.z); u1.w=f2b(v1.w);
      *(ushort4*)&Tl[row][cc * 8]     = u0;
      *(ushort4*)&Tl[row][cc * 8 + 4] = u1;
    }
  }
  __syncthreads();
  int lane = tid & 63, wave = tid >> 6;    // 8 waves
  int la = lane & 31, hi = lane >> 5;
  int n0 = (wave & 3) * 32;                // col slab
  int r0 = (wave >> 2) * 32;               // row half
  f32x16 acc{};
  const unsigned short* w1p = W1T + (size_t)(n0 + la) * 384 + hi * 8;
#pragma unroll
  for (int ks = 0; ks < 16; ++ks) {        // K 0..255 from Ah
    bf16x8 a = *(const bf16x8*)&Ah[r0 + la][ks * 16 + hi * 8];
    bf16x8 b = *(const bf16x8*)(w1p + ks * 16);
    acc = mfma32(a, b, acc);
  }
#pragma unroll
  for (int ks = 0; ks < 8; ++ks) {         // K 256..383 from Tl
    bf16x8 a = *(const bf16x8*)&Tl[r0 + la][ks * 16 + hi * 8];
    bf16x8 b = *(const bf16x8*)(w1p + 256 + ks * 16);
    acc = mfma32(a, b, acc);
  }
  __syncthreads();                         // all Ah reads done; reuse as Y
  unsigned short* Y = &Ah[0][0];           // view [64][136]
  float b1v = be1[n0 + la];
#pragma unroll
  for (int r = 0; r < 16; ++r) {
    int row = r0 + (r & 3) + 8 * (r >> 2) + 4 * hi;
    float v = acc[r] + b1v;
    Y[row * 136 + n0 + la] = f2b(silu_fast(v));
  }
  __syncthreads();
  f32x16 c0{};
  const unsigned short* w2p = W2T + (size_t)(n0 + la) * DD + hi * 8;
#pragma unroll
  for (int ks = 0; ks < 8; ++ks) {
    bf16x8 a = *(const bf16x8*)&Y[(r0 + la) * 136 + ks * 16 + hi * 8];
    bf16x8 b = *(const bf16x8*)(w2p + ks * 16);
    c0 = mfma32(a, b, c0);
  }
  float b2v = be2[n0 + la];
#pragma unroll
  for (int r = 0; r < 16; ++r) {
    int row = r0 + (r & 3) + 8 * (r >> 2) + 4 * hi;
    t_out[(size_t)(e0 + row) * DD + n0 + la] = b2f(Tl[row][n0 + la]) + c0[r] + b2v;
  }
}

extern "C" void kernel_launch(void* const* d_in, const int* in_sizes, int n_in,
                              void* d_out, int out_size, void* d_ws, size_t ws_size,
                              hipStream_t stream)
{
  const int*   ei   = (const int*)d_in[0];
  const float* h    = (const float*)d_in[1];
  const float* t_ij = (const float*)d_in[2];
  const float* Wq = (const float*)d_in[3];
  const float* bq = (const float*)d_in[4];
  const float* Wk = (const float*)d_in[5];
  const float* bk = (const float*)d_in[6];
  const float* Wv = (const float*)d_in[7];
  const float* bv = (const float*)d_in[8];
  const float* Wg = (const float*)d_in[9];
  const float* bg = (const float*)d_in[10];
  const float* Wo = (const float*)d_in[11];
  const float* bo = (const float*)d_in[12];
  const float* We1 = (const float*)d_in[13];
  const float* be1 = (const float*)d_in[14];
  const float* We2 = (const float*)d_in[15];
  const float* be2 = (const float*)d_in[16];

  char* base = (char*)d_ws;
  size_t o = 0;
  auto take = [&](size_t bytes) -> void* {
    void* p = base + o;
    o = (o + bytes + 255) & ~(size_t)255;
    return p;
  };
  float* Q       = (float*)take((size_t)NN * DD * 4);
  float* K       = (float*)take((size_t)NN * DD * 4);
  float* V       = (float*)take((size_t)NN * DD * 4);
  float* logitsT = (float*)take((size_t)NH * NE * 4);
  float* partial = (float*)take(512 * 4);
  float* rs      = (float*)take(256);
  float* h_agg   = (float*)take((size_t)NN * DD * 4);
  // zero region: deg + cursor contiguous
  char* zbase = base + o;
  int* deg    = (int*)zbase;
  int* cursor = (int*)(zbase + (size_t)NN * 4);
  size_t zbytes = (size_t)NN * 4 * 2;
  o = (o + zbytes + 255) & ~(size_t)255;
  int* offs  = (int*)take((size_t)(NN + 1) * 4);
  int* elist = (int*)take((size_t)NE * 4);
  unsigned short* hnb = (unsigned short*)take((size_t)NN * DD * 2);
  unsigned short* W1T = (unsigned short*)take(384 * 128 * 2);
  unsigned short* W2T = (unsigned short*)take(128 * 128 * 2);
  unsigned short* WgT = (unsigned short*)take(32 * 128 * 2);
  unsigned short* tb  = (unsigned short*)take((size_t)NE * DD * 2);
  bool use_tb = (o <= ws_size);   // fall back to re-reading f32 t if ws too small

  float* out_h = (float*)d_out;
  float* t_out = out_h + (size_t)NN * DD;

  hipMemsetAsync(zbase, 0, zbytes, stream);
  prep_weights_k<<<272, 256, 0, stream>>>(We1, We2, Wg, W1T, W2T, WgT);
  node_proj_k<<<NN / 4, 128, 0, stream>>>(h, Wq, bq, Wk, bk, Wv, bv, Q, K, V);
  qk_k<<<NE / 32, 256, 0, stream>>>(ei, Q, K, bg, logitsT, deg);
  t_gate_k<<<NE / 32, 64, 0, stream>>>(t_ij, tb, WgT, logitsT, use_tb ? 1 : 0);
  sumexp_part_k<<<dim3(64, 8), 256, 0, stream>>>(logitsT, partial);
  sumexp_fin_k<<<1, 64, 0, stream>>>(partial, rs);
  scan_k<<<1, 1024, 0, stream>>>(deg, offs);
  bucket_k<<<NE / 256, 256, 0, stream>>>(ei, offs, cursor, elist);
  aggregate_k<<<NN, 128, 0, stream>>>(ei, offs, elist, logitsT, rs, V, h_agg);
  hnew_k<<<NN / 4, 128, 0, stream>>>(h, h_agg, Wo, bo, out_h, hnb);
  if (use_tb)
    edge_mlp_k<true><<<NE / 64, 512, 0, stream>>>(ei, hnb, tb, t_ij, W1T, W2T, be1, be2, t_out);
  else
    edge_mlp_k<false><<<NE / 64, 512, 0, stream>>>(ei, hnb, tb, t_ij, W1T, W2T, be1, be2, t_out);
}

// Round 3
// 387.125 us; speedup vs baseline: 1.2278x; 1.2278x over previous
//
#include <hip/hip_runtime.h>

#define NN 10000      // nodes
#define NE 320000     // edges
#define DD 128        // feature dim
#define NH 8          // heads

typedef __attribute__((ext_vector_type(8)))  __bf16        bf16x8;
typedef __attribute__((ext_vector_type(8)))  unsigned short ushort8v;
typedef __attribute__((ext_vector_type(16))) float         f32x16;

__device__ __forceinline__ unsigned short f2b(float f) {
  unsigned int b = __builtin_bit_cast(unsigned int, f);
  b += 0x7FFFu + ((b >> 16) & 1u);          // RNE to bf16
  return (unsigned short)(b >> 16);
}
__device__ __forceinline__ float b2f(unsigned short u) {
  return __builtin_bit_cast(float, (unsigned int)u << 16);
}
__device__ __forceinline__ f32x16 mfma32(bf16x8 a, bf16x8 b, f32x16 c) {
  return __builtin_amdgcn_mfma_f32_32x32x16_bf16(a, b, c, 0, 0, 0);
}
__device__ __forceinline__ float exp_fast(float x) {
  return __builtin_amdgcn_exp2f(x * 1.44269504f);
}
__device__ __forceinline__ float silu_fast(float x) {
  float e = __builtin_amdgcn_exp2f(x * -1.44269504f);
  return x * __builtin_amdgcn_rcpf(1.0f + e);
}

// ---- weights -> bf16, FRAGMENT-MAJOR for coalesced in-loop loads ----
// W1F[((slab*24+ks)*64+lane)*8+j] = We1[k][n], k=ks*16+(lane>>5)*8+j, n=slab*32+(lane&31)
// W2F analogous with 8 K-steps. WgT stays [n][k] padded 8->32 cols.
__global__ __launch_bounds__(256) void prep_weights_k(
    const float* We1, const float* We2, const float* Wg,
    unsigned short* W1F, unsigned short* W2F, unsigned short* WgT)
{
  int idx = blockIdx.x * 256 + threadIdx.x;
  if (idx < 49152) {                       // 4*24*64*8
    int j = idx & 7, lane = (idx >> 3) & 63;
    int ks = (idx >> 9) % 24, slab = idx / (24 * 512);
    int k = ks * 16 + (lane >> 5) * 8 + j;
    int n = slab * 32 + (lane & 31);
    W1F[idx] = f2b(We1[k * 128 + n]);
  } else if (idx < 49152 + 16384) {        // 4*8*64*8
    int o = idx - 49152;
    int j = o & 7, lane = (o >> 3) & 63;
    int ks = (o >> 9) & 7, slab = o >> 12;
    int k = ks * 16 + (lane >> 5) * 8 + j;
    int n = slab * 32 + (lane & 31);
    W2F[o] = f2b(We2[k * 128 + n]);
  } else if (idx < 49152 + 16384 + 4096) {
    int o = idx - (49152 + 16384);
    int n = o >> 7, k = o & 127;
    WgT[o] = (n < 8) ? f2b(Wg[k * 8 + n]) : (unsigned short)0;
  }
}

// ---- per-node Q/K/V projections (f32), 4 nodes per 128-thread block ----
__global__ __launch_bounds__(128) void node_proj_k(
    const float* h, const float* Wq, const float* bq,
    const float* Wk, const float* bk, const float* Wv, const float* bv,
    float* Q, float* K, float* V)
{
  __shared__ float hs[4][132];
  int g = threadIdx.x >> 5, la = threadIdx.x & 31;
  int n = blockIdx.x * 4 + g;
  float4 hv = *(const float4*)(h + (size_t)n * DD + la * 4);
  hs[g][la*4+0] = hv.x; hs[g][la*4+1] = hv.y; hs[g][la*4+2] = hv.z; hs[g][la*4+3] = hv.w;
  __syncthreads();
  float4 q = *(const float4*)(bq + la * 4);
  float4 k = *(const float4*)(bk + la * 4);
  float4 v = *(const float4*)(bv + la * 4);
  for (int kk = 0; kk < DD; ++kk) {
    float a = hs[g][kk];
    float4 wq = *(const float4*)(Wq + (size_t)kk * DD + la * 4);
    float4 wk = *(const float4*)(Wk + (size_t)kk * DD + la * 4);
    float4 wv = *(const float4*)(Wv + (size_t)kk * DD + la * 4);
    q.x += a * wq.x; q.y += a * wq.y; q.z += a * wq.z; q.w += a * wq.w;
    k.x += a * wk.x; k.y += a * wk.y; k.z += a * wk.z; k.w += a * wk.w;
    v.x += a * wv.x; v.y += a * wv.y; v.z += a * wv.z; v.w += a * wv.w;
  }
  *(float4*)(Q + (size_t)n * DD + la * 4) = q;
  *(float4*)(K + (size_t)n * DD + la * 4) = k;
  *(float4*)(V + (size_t)n * DD + la * 4) = v;
}

// ---- logitsT[h][e] = qk/4 + bg; also builds dst-degree histogram ----
__global__ __launch_bounds__(256) void qk_k(const int* ei, const float* Q, const float* K,
                                            const float* bg, float* logitsT, int* deg)
{
  int e  = blockIdx.x * 32 + (threadIdx.x & 31);
  int h8 = threadIdx.x >> 5;
  int s  = ei[e];
  int d2 = ei[NE + e];
  if (h8 == 0) atomicAdd(&deg[d2], 1);
  const float4* qr = (const float4*)(Q + (size_t)d2 * DD + h8 * 16);
  const float4* kr = (const float4*)(K + (size_t)s  * DD + h8 * 16);
  float acc = 0.f;
#pragma unroll
  for (int i = 0; i < 4; ++i) {
    float4 a = qr[i], b = kr[i];
    acc += a.x*b.x + a.y*b.y + a.z*b.z + a.w*b.w;
  }
  logitsT[(size_t)h8 * NE + e] = acc * 0.25f + bg[h8];
}

// ---- convert t->bf16 (store) + gate via MFMA, add into logitsT. 128 edges/block ----
__global__ __launch_bounds__(256) void t_gate_k(const float* t_ij, unsigned short* tb,
                                                const unsigned short* WgT, float* logitsT,
                                                int write_tb)
{
  __shared__ unsigned short T[128][136];
  int e0 = blockIdx.x * 128;
  int tid = threadIdx.x;
  const float4* tp = (const float4*)(t_ij + (size_t)e0 * DD);
#pragma unroll
  for (int i = 0; i < 16; ++i) {
    int gi = tid + i * 256;          // 4096 float4 = 128 rows x 32
    float4 v = tp[gi];
    int row = gi >> 5, c4 = gi & 31;
    ushort4 u; u.x = f2b(v.x); u.y = f2b(v.y); u.z = f2b(v.z); u.w = f2b(v.w);
    *(ushort4*)&T[row][c4 * 4] = u;
    if (write_tb) *(ushort4*)(tb + (size_t)(e0 + row) * DD + c4 * 4) = u;
  }
  __syncthreads();
  int wave = tid >> 6, lane = tid & 63;
  int la = lane & 31, hi = lane >> 5;
  int r0 = wave * 32;
  f32x16 acc{};
  const unsigned short* wp = WgT + (size_t)la * DD + hi * 8;
#pragma unroll
  for (int ks = 0; ks < 8; ++ks) {
    bf16x8 a = *(const bf16x8*)&T[r0 + la][ks * 16 + hi * 8];
    bf16x8 b = *(const bf16x8*)(wp + ks * 16);
    acc = mfma32(a, b, acc);
  }
  if (la < 8) {
#pragma unroll
    for (int r = 0; r < 16; ++r) {
      int row = r0 + (r & 3) + 8 * (r >> 2) + 4 * hi;
      logitsT[(size_t)la * NE + e0 + row] += acc[r];
    }
  }
}

// ---- global per-head softmax denominator; stores exp(logit) back in place ----
__global__ __launch_bounds__(256) void sumexp_part_k(float* logitsT, float* partial) {
  int hh = blockIdx.y, b = blockIdx.x;
  float* p = logitsT + (size_t)hh * NE + (size_t)b * 5000;
  float s = 0.f;
  for (int i = threadIdx.x; i < 5000; i += 256) {
    float ex = exp_fast(p[i]);
    p[i] = ex;
    s += ex;
  }
  __shared__ float red[256];
  red[threadIdx.x] = s;
  __syncthreads();
  for (int k = 128; k > 0; k >>= 1) {
    if (threadIdx.x < k) red[threadIdx.x] += red[threadIdx.x + k];
    __syncthreads();
  }
  if (threadIdx.x == 0) partial[hh * 64 + b] = red[0];
}

__global__ void sumexp_fin_k(const float* partial, float* rs) {
  int hh = threadIdx.x;
  if (hh < 8) {
    float s = 0.f;
    for (int i = 0; i < 64; ++i) s += partial[hh * 64 + i];
    rs[hh] = 1.0f / s;
  }
}

// ---- single-block shuffle scan over deg -> exclusive offs ----
__global__ __launch_bounds__(1024) void scan_k(const int* deg, int* offs) {
  __shared__ int ws[16];
  __shared__ int tot;
  int tid = threadIdx.x;
  int base = tid * 10;
  int v[10]; int s = 0;
#pragma unroll
  for (int j = 0; j < 10; ++j) {
    int i = base + j;
    int d = (i < NN) ? deg[i] : 0;
    v[j] = s; s += d;
  }
  int x = s;
#pragma unroll
  for (int off = 1; off < 64; off <<= 1) {
    int y = __shfl_up(x, off, 64);
    if ((tid & 63) >= off) x += y;        // inclusive wave scan
  }
  if ((tid & 63) == 63) ws[tid >> 6] = x;
  __syncthreads();
  if (tid == 0) {
    int c = 0;
#pragma unroll
    for (int k = 0; k < 16; ++k) { int t = ws[k]; ws[k] = c; c += t; }
    tot = c;
  }
  __syncthreads();
  int texcl = ws[tid >> 6] + (x - s);     // exclusive prefix of this thread's chunk
#pragma unroll
  for (int j = 0; j < 10; ++j) {
    int i = base + j;
    if (i < NN) offs[i] = texcl + v[j];
  }
  if (tid == 0) offs[NN] = tot;
}

__global__ __launch_bounds__(256) void bucket_k(const int* ei, const int* offs,
                                                int* cursor, int2* elist2) {
  int e = blockIdx.x * 256 + threadIdx.x;
  int s = ei[e];
  int d2 = ei[NE + e];
  int p = atomicAdd(&cursor[d2], 1);
  int2 es; es.x = e; es.y = s;
  elist2[offs[d2] + p] = es;
}

// ---- gather-sum per node: h_agg[n][d] = rs * sum_e expL[e][d/16] * V[src[e]][d] ----
__global__ __launch_bounds__(128) void aggregate_k(const int* offs, const int2* elist2,
                                                   const float* expT, const float* rs,
                                                   const float* V, float* h_agg)
{
  int n = blockIdx.x, d = threadIdx.x;
  float rsv = rs[d >> 4];
  const float* aT = expT + (size_t)(d >> 4) * NE;
  int st = offs[n], en = offs[n + 1];
  float acc = 0.f;
  for (int i = st; i < en; ++i) {
    int2 es = elist2[i];
    acc += aT[es.x] * V[(size_t)es.y * DD + d];
  }
  h_agg[(size_t)n * DD + d] = acc * rsv;
}

// ---- h_new = h + h_agg @ Wo + bo  (f32 to d_out, bf16 copy for MLP) ----
__global__ __launch_bounds__(128) void hnew_k(const float* h, const float* h_agg,
                                              const float* Wo, const float* bo,
                                              float* out_h, unsigned short* hnb)
{
  __shared__ float ag[4][132];
  int g = threadIdx.x >> 5, la = threadIdx.x & 31;
  int n = blockIdx.x * 4 + g;
  float4 av = *(const float4*)(h_agg + (size_t)n * DD + la * 4);
  ag[g][la*4+0] = av.x; ag[g][la*4+1] = av.y; ag[g][la*4+2] = av.z; ag[g][la*4+3] = av.w;
  __syncthreads();
  float4 acc = *(const float4*)(bo + la * 4);
  for (int kk = 0; kk < DD; ++kk) {
    float a = ag[g][kk];
    float4 w = *(const float4*)(Wo + (size_t)kk * DD + la * 4);
    acc.x += a * w.x; acc.y += a * w.y; acc.z += a * w.z; acc.w += a * w.w;
  }
  float4 hv = *(const float4*)(h + (size_t)n * DD + la * 4);
  acc.x += hv.x; acc.y += hv.y; acc.z += hv.z; acc.w += hv.w;
  *(float4*)(out_h + (size_t)n * DD + la * 4) = acc;
  ushort4 u; u.x = f2b(acc.x); u.y = f2b(acc.y); u.z = f2b(acc.z); u.w = f2b(acc.w);
  *(ushort4*)(hnb + (size_t)n * DD + la * 4) = u;
}

// ---- edge MLP: t_out = t + silu([hn[src],hn[dst],t] @ We1 + be1) @ We2 + be2 ----
// 64 edges/block, 4 waves, each wave owns 32 output cols, two 32-row acc chains.
// Weights read fragment-major (coalesced 1KB/load).
template <bool TB>
__global__ __launch_bounds__(256) void edge_mlp_k(
    const int* ei, const unsigned short* hnb, const unsigned short* tb, const float* t_ij,
    const unsigned short* W1F, const unsigned short* W2F,
    const float* be1, const float* be2, float* t_out)
{
  __shared__ unsigned short Ah[64][264];   // cols 0..255 = h_src | h_dst (then reused as Y)
  __shared__ unsigned short Tl[64][136];   // t section (kept for epilogue residual)
  __shared__ int sd[128];
  int tid = threadIdx.x;
  int e0 = blockIdx.x * 64;
  if (tid < 128) sd[tid] = (tid < 64) ? ei[e0 + tid] : ei[NE + e0 + tid - 64];
  __syncthreads();
#pragma unroll
  for (int i = 0; i < 8; ++i) {            // 2048 16B chunks for the two h sections
    int c = tid + i * 256;
    int sec = c >> 10;
    int row = (c >> 4) & 63;
    int cc = c & 15;
    int node = sd[sec * 64 + row];
    ushort8v val = *(const ushort8v*)(hnb + (size_t)node * DD + cc * 8);
    *(ushort8v*)&Ah[row][sec * 128 + cc * 8] = val;
  }
  if (TB) {
#pragma unroll
    for (int i = 0; i < 4; ++i) {
      int c = tid + i * 256;
      int row = c >> 4, cc = c & 15;
      *(ushort8v*)&Tl[row][cc * 8] = *(const ushort8v*)(tb + (size_t)(e0 + row) * DD + cc * 8);
    }
  } else {
#pragma unroll
    for (int i = 0; i < 4; ++i) {
      int c = tid + i * 256;
      int row = c >> 4, cc = c & 15;
      const float4* fp = (const float4*)(t_ij + (size_t)(e0 + row) * DD + cc * 8);
      float4 v0 = fp[0], v1 = fp[1];
      ushort4 u0; u0.x=f2b(v0.x); u0.y=f2b(v0.y); u0.z=f2b(v0.z); u0.w=f2b(v0.w);
      ushort4 u1; u1.x=f2b(v1.x); u1.y=f2b(v1.y); u1.z=f2b(v1.z); u1.w=f2b(v1.w);
      *(ushort4*)&Tl[row][cc * 8]     = u0;
      *(ushort4*)&Tl[row][cc * 8 + 4] = u1;
    }
  }
  __syncthreads();
  int lane = tid & 63, wave = tid >> 6;
  int la = lane & 31, hi = lane >> 5;
  int n0 = wave * 32;
  f32x16 acc0{}, acc1{};
  const unsigned short* w1p = W1F + (((size_t)wave * 24) << 9) + lane * 8;
#pragma unroll 4
  for (int ks = 0; ks < 16; ++ks) {        // K 0..255 from Ah
    bf16x8 a0 = *(const bf16x8*)&Ah[la][ks * 16 + hi * 8];
    bf16x8 a1 = *(const bf16x8*)&Ah[la + 32][ks * 16 + hi * 8];
    bf16x8 b  = *(const bf16x8*)(w1p + (ks << 9));
    acc0 = mfma32(a0, b, acc0);
    acc1 = mfma32(a1, b, acc1);
  }
#pragma unroll 4
  for (int ks = 0; ks < 8; ++ks) {         // K 256..383 from Tl
    bf16x8 a0 = *(const bf16x8*)&Tl[la][ks * 16 + hi * 8];
    bf16x8 a1 = *(const bf16x8*)&Tl[la + 32][ks * 16 + hi * 8];
    bf16x8 b  = *(const bf16x8*)(w1p + ((16 + ks) << 9));
    acc0 = mfma32(a0, b, acc0);
    acc1 = mfma32(a1, b, acc1);
  }
  __syncthreads();                         // all Ah reads done; reuse as Y
  unsigned short* Y = &Ah[0][0];           // view [64][136]
  float b1v = be1[n0 + la];
#pragma unroll
  for (int r = 0; r < 16; ++r) {
    int row = (r & 3) + 8 * (r >> 2) + 4 * hi;
    Y[row * 136 + n0 + la]        = f2b(silu_fast(acc0[r] + b1v));
    Y[(row + 32) * 136 + n0 + la] = f2b(silu_fast(acc1[r] + b1v));
  }
  __syncthreads();
  f32x16 c0{}, c1{};
  const unsigned short* w2p = W2F + (((size_t)wave * 8) << 9) + lane * 8;
#pragma unroll 4
  for (int ks = 0; ks < 8; ++ks) {
    bf16x8 a0 = *(const bf16x8*)&Y[la * 136 + ks * 16 + hi * 8];
    bf16x8 a1 = *(const bf16x8*)&Y[(la + 32) * 136 + ks * 16 + hi * 8];
    bf16x8 b  = *(const bf16x8*)(w2p + (ks << 9));
    c0 = mfma32(a0, b, c0);
    c1 = mfma32(a1, b, c1);
  }
  float b2v = be2[n0 + la];
#pragma unroll
  for (int r = 0; r < 16; ++r) {
    int row = (r & 3) + 8 * (r >> 2) + 4 * hi;
    t_out[(size_t)(e0 + row) * DD + n0 + la]      = b2f(Tl[row][n0 + la])      + c0[r] + b2v;
    t_out[(size_t)(e0 + row + 32) * DD + n0 + la] = b2f(Tl[row + 32][n0 + la]) + c1[r] + b2v;
  }
}

extern "C" void kernel_launch(void* const* d_in, const int* in_sizes, int n_in,
                              void* d_out, int out_size, void* d_ws, size_t ws_size,
                              hipStream_t stream)
{
  const int*   ei   = (const int*)d_in[0];
  const float* h    = (const float*)d_in[1];
  const float* t_ij = (const float*)d_in[2];
  const float* Wq = (const float*)d_in[3];
  const float* bq = (const float*)d_in[4];
  const float* Wk = (const float*)d_in[5];
  const float* bk = (const float*)d_in[6];
  const float* Wv = (const float*)d_in[7];
  const float* bv = (const float*)d_in[8];
  const float* Wg = (const float*)d_in[9];
  const float* bg = (const float*)d_in[10];
  const float* Wo = (const float*)d_in[11];
  const float* bo = (const float*)d_in[12];
  const float* We1 = (const float*)d_in[13];
  const float* be1 = (const float*)d_in[14];
  const float* We2 = (const float*)d_in[15];
  const float* be2 = (const float*)d_in[16];

  char* base = (char*)d_ws;
  size_t o = 0;
  auto take = [&](size_t bytes) -> void* {
    void* p = base + o;
    o = (o + bytes + 255) & ~(size_t)255;
    return p;
  };
  float* Q       = (float*)take((size_t)NN * DD * 4);
  float* K       = (float*)take((size_t)NN * DD * 4);
  float* V       = (float*)take((size_t)NN * DD * 4);
  float* logitsT = (float*)take((size_t)NH * NE * 4);
  float* partial = (float*)take(512 * 4);
  float* rs      = (float*)take(256);
  float* h_agg   = (float*)take((size_t)NN * DD * 4);
  // zero region: deg + cursor contiguous
  char* zbase = base + o;
  int* deg    = (int*)zbase;
  int* cursor = (int*)(zbase + (size_t)NN * 4);
  size_t zbytes = (size_t)NN * 4 * 2;
  o = (o + zbytes + 255) & ~(size_t)255;
  int* offs    = (int*)take((size_t)(NN + 1) * 4);
  int2* elist2 = (int2*)take((size_t)NE * 8);
  unsigned short* hnb = (unsigned short*)take((size_t)NN * DD * 2);
  unsigned short* W1F = (unsigned short*)take(49152 * 2);
  unsigned short* W2F = (unsigned short*)take(16384 * 2);
  unsigned short* WgT = (unsigned short*)take(4096 * 2);
  unsigned short* tb  = (unsigned short*)take((size_t)NE * DD * 2);
  bool use_tb = (o <= ws_size);   // fall back to re-reading f32 t if ws too small

  float* out_h = (float*)d_out;
  float* t_out = out_h + (size_t)NN * DD;

  hipMemsetAsync(zbase, 0, zbytes, stream);
  prep_weights_k<<<272, 256, 0, stream>>>(We1, We2, Wg, W1F, W2F, WgT);
  node_proj_k<<<NN / 4, 128, 0, stream>>>(h, Wq, bq, Wk, bk, Wv, bv, Q, K, V);
  qk_k<<<NE / 32, 256, 0, stream>>>(ei, Q, K, bg, logitsT, deg);
  t_gate_k<<<NE / 128, 256, 0, stream>>>(t_ij, tb, WgT, logitsT, use_tb ? 1 : 0);
  sumexp_part_k<<<dim3(64, 8), 256, 0, stream>>>(logitsT, partial);
  sumexp_fin_k<<<1, 64, 0, stream>>>(partial, rs);
  scan_k<<<1, 1024, 0, stream>>>(deg, offs);
  bucket_k<<<NE / 256, 256, 0, stream>>>(ei, offs, cursor, elist2);
  aggregate_k<<<NN, 128, 0, stream>>>(offs, elist2, logitsT, rs, V, h_agg);
  hnew_k<<<NN / 4, 128, 0, stream>>>(h, h_agg, Wo, bo, out_h, hnb);
  if (use_tb)
    edge_mlp_k<true><<<NE / 64, 256, 0, stream>>>(ei, hnb, tb, t_ij, W1F, W2F, be1, be2, t_out);
  else
    edge_mlp_k<false><<<NE / 64, 256, 0, stream>>>(ei, hnb, tb, t_ij, W1F, W2F, be1, be2, t_out);
}